// Round 1
// baseline (245.703 us; speedup 1.0000x reference)
//
#include <hip/hip_runtime.h>

#define AS1(p) ((const __attribute__((address_space(1))) void*)(p))
#define AS3(p) ((__attribute__((address_space(3))) void*)(p))

typedef unsigned short u16;
typedef __bf16 bf16x8 __attribute__((ext_vector_type(8)));
typedef short s16x8 __attribute__((ext_vector_type(8)));
typedef float f32x4 __attribute__((ext_vector_type(4)));
typedef unsigned short u16x4 __attribute__((ext_vector_type(4)));

__device__ __forceinline__ u16 f2bf(float x) {
    unsigned u = __float_as_uint(x);
    unsigned r = (u + 0x7FFFu + ((u >> 16) & 1u)) >> 16;
    return (u16)r;
}

// ---- MFMA wrapper: tolerate either V8bf16 or V8i16 builtin signature ----
template <typename V8>
__device__ __forceinline__ auto mfma_sel(V8 a, V8 b, f32x4 c, int)
    -> decltype(__builtin_amdgcn_mfma_f32_16x16x32_bf16(a, b, c, 0, 0, 0))
{
    return __builtin_amdgcn_mfma_f32_16x16x32_bf16(a, b, c, 0, 0, 0);
}
template <typename V8>
__device__ __forceinline__ f32x4 mfma_sel(V8 a, V8 b, f32x4 c, long)
{
    s16x8 a2 = __builtin_bit_cast(s16x8, a);
    s16x8 b2 = __builtin_bit_cast(s16x8, b);
    return __builtin_amdgcn_mfma_f32_16x16x32_bf16(a2, b2, c, 0, 0, 0);
}
__device__ __forceinline__ f32x4 mfma16x16x32(bf16x8 a, bf16x8 b, f32x4 c)
{
    return mfma_sel(a, b, c, 0);
}

// ---------------- fp32 -> bf16 convert ----------------
__global__ __launch_bounds__(256) void cvt_bf16_kernel(const float* __restrict__ in,
                                                       u16* __restrict__ out, int n4)
{
    int i = blockIdx.x * 256 + threadIdx.x;
    if (i >= n4) return;
    float4 f = ((const float4*)in)[i];
    u16x4 o;
    o.x = f2bf(f.x); o.y = f2bf(f.y); o.z = f2bf(f.z); o.w = f2bf(f.w);
    ((u16x4*)out)[i] = o;
}

// ---------------- NT GEMM: C[m][n] = sum_k A[m][k]*B[n][k] ----------------
// BIAS: 0 none, 1 bias[col], 2 bias[row].  OUTBF16: output dtype.
// CSKIP: skip blocks fully above causal diagonal (scores).
// CKB:   bound K at m0+BM (PV with causal-zeroed P).
#define BM 128
#define BN 128
#define BK 64

template <int BIAS, int OUTBF16, int CSKIP, int CKB>
__global__ __launch_bounds__(256, 2)
void gemm_nt(const u16* __restrict__ A, const u16* __restrict__ B,
             void* __restrict__ Cv, const float* __restrict__ bias,
             int M, int N, int K, int lda, int ldb, int ldc,
             long long sA, long long sB, long long sC, float scale)
{
    __shared__ u16 lA[BM * BK];
    __shared__ u16 lB[BN * BK];

    const int m0 = blockIdx.y * BM;
    const int n0 = blockIdx.x * BN;
    if (CSKIP && n0 > m0 + BM - 1) return;

    const int z = blockIdx.z;
    A += (size_t)z * (size_t)sA;
    B += (size_t)z * (size_t)sB;

    const int t = threadIdx.x;
    const int lane = t & 63;
    const int w = t >> 6;
    const int wr = w >> 1, wc = w & 1;
    const int fr = lane & 15, fg = lane >> 4;

    int Keff = K;
    if (CKB) { Keff = m0 + BM; if (Keff > K) Keff = K; }

    f32x4 acc[4][4] = {};

    for (int k0 = 0; k0 < Keff; k0 += BK) {
        // ---- stage A,B tiles (128x64 bf16 each) via global_load_lds x16 ----
        #pragma unroll
        for (int p = 0; p < 4; ++p) {
            int e = (p * 4096 + t * 16) >> 1;   // element offset in tile
            int row = e >> 6;                   // /BK
            int col = e & (BK - 1);
            __builtin_amdgcn_global_load_lds(
                AS1(A + (size_t)(m0 + row) * lda + k0 + col), AS3(&lA[e]), 16, 0, 0);
            __builtin_amdgcn_global_load_lds(
                AS1(B + (size_t)(n0 + row) * ldb + k0 + col), AS3(&lB[e]), 16, 0, 0);
        }
        __syncthreads();

        // ---- compute: each wave owns 64x64 = 4x4 fragments ----
        #pragma unroll
        for (int kk = 0; kk < BK; kk += 32) {
            bf16x8 af[4], bfr[4];
            #pragma unroll
            for (int mi = 0; mi < 4; ++mi)
                af[mi] = *(const bf16x8*)&lA[(wr * 64 + mi * 16 + fr) * BK + kk + fg * 8];
            #pragma unroll
            for (int ni = 0; ni < 4; ++ni)
                bfr[ni] = *(const bf16x8*)&lB[(wc * 64 + ni * 16 + fr) * BK + kk + fg * 8];
            #pragma unroll
            for (int mi = 0; mi < 4; ++mi)
                #pragma unroll
                for (int ni = 0; ni < 4; ++ni)
                    acc[mi][ni] = mfma16x16x32(af[mi], bfr[ni], acc[mi][ni]);
        }
        __syncthreads();
    }

    // ---- epilogue: C/D layout col=lane&15, row=(lane>>4)*4+reg ----
    #pragma unroll
    for (int mi = 0; mi < 4; ++mi) {
        #pragma unroll
        for (int ni = 0; ni < 4; ++ni) {
            int col = n0 + wc * 64 + ni * 16 + fr;
            float bcol = (BIAS == 1) ? bias[col] : 0.f;
            #pragma unroll
            for (int j = 0; j < 4; ++j) {
                int row = m0 + wr * 64 + mi * 16 + fg * 4 + j;
                float v = acc[mi][ni][j];
                if (BIAS == 1) v += bcol;
                else if (BIAS == 2) v += bias[row];
                v *= scale;
                size_t off = (size_t)z * (size_t)sC + (size_t)row * ldc + col;
                if (OUTBF16) ((u16*)Cv)[off] = f2bf(v);
                else         ((float*)Cv)[off] = v;
            }
        }
    }
}

// ---------------- causal softmax, in-place fp32 -> bf16 P ----------------
__device__ __forceinline__ float waveMax(float v) {
    #pragma unroll
    for (int o = 32; o > 0; o >>= 1) v = fmaxf(v, __shfl_xor(v, o));
    return v;
}
__device__ __forceinline__ float waveSum(float v) {
    #pragma unroll
    for (int o = 32; o > 0; o >>= 1) v += __shfl_xor(v, o);
    return v;
}

__global__ __launch_bounds__(256) void softmax_causal_kernel(float* __restrict__ scores, int S)
{
    __shared__ float red[4];
    const int gb = blockIdx.x;
    const int b = gb / S;
    const int i = gb - b * S;
    float* srow = scores + (size_t)b * S * S + (size_t)i * S;
    u16* prow = (u16*)srow;  // overwrite first half of the fp32 row with bf16 P
    const int t = threadIdx.x;
    const int jlim = ((i >> 7) + 1) << 7;   // computed-region end (tile-rounded)

    float vals[8];
    float mx = -1e30f;
    #pragma unroll
    for (int s = 0; s < 8; ++s) {
        int j = t + (s << 8);
        float x = -1e30f;
        if (j <= i) x = srow[j];
        vals[s] = x;
        mx = fmaxf(mx, x);
    }
    mx = waveMax(mx);
    const int wv = t >> 6;
    if ((t & 63) == 0) red[wv] = mx;
    __syncthreads();
    mx = fmaxf(fmaxf(red[0], red[1]), fmaxf(red[2], red[3]));
    __syncthreads();

    float sum = 0.f;
    #pragma unroll
    for (int s = 0; s < 8; ++s) {
        float e = (vals[s] > -1e29f) ? __expf(vals[s] - mx) : 0.f;
        vals[s] = e;
        sum += e;
    }
    sum = waveSum(sum);
    if ((t & 63) == 0) red[wv] = sum;
    __syncthreads();
    sum = red[0] + red[1] + red[2] + red[3];
    const float inv = 1.f / sum;
    __syncthreads();   // all reads of srow complete before aliased bf16 writes

    #pragma unroll
    for (int s = 0; s < 8; ++s) {
        int j = t + (s << 8);
        if (j < jlim) prow[j] = f2bf(vals[s] * inv);
    }
}

// ---------------- host launcher ----------------
extern "C" void kernel_launch(void* const* d_in, const int* in_sizes, int n_in,
                              void* d_out, int out_size, void* d_ws, size_t ws_size,
                              hipStream_t stream)
{
    (void)in_sizes; (void)n_in; (void)out_size;
    const float* x  = (const float*)d_in[0];
    const float* Wq = (const float*)d_in[1];
    const float* bq = (const float*)d_in[2];
    const float* Wk = (const float*)d_in[3];
    const float* bk = (const float*)d_in[4];
    const float* Wv = (const float*)d_in[5];
    const float* bv = (const float*)d_in[6];
    const float* Wp = (const float*)d_in[7];
    const float* bp = (const float*)d_in[8];

    const int D = 1024, S = 2048, B = 4;
    const int M = B * S; // 8192

    char* p = (char*)d_ws;
    u16* xb  = (u16*)p; p += (size_t)M * D * 2;
    u16* Wqb = (u16*)p; p += (size_t)D * D * 2;
    u16* Wkb = (u16*)p; p += (size_t)D * D * 2;
    u16* Wvb = (u16*)p; p += (size_t)D * D * 2;
    u16* Wpb = (u16*)p; p += (size_t)D * D * 2;
    u16* qb  = (u16*)p; p += (size_t)M * D * 2;
    u16* kb  = (u16*)p; p += (size_t)M * D * 2;
    u16* vTb = (u16*)p; p += (size_t)M * D * 2;   // vT[d][b*S+s], ld = M
    float* sc = (float*)p;                        // scores: up to B*S*S fp32
    u16* attnb = xb;                              // alias: x dead after QKV GEMMs

    const size_t fixed = (size_t)p - (size_t)d_ws;
    const size_t sb1 = (size_t)S * S * 4;
    int zb = (ws_size >= fixed + 4 * sb1) ? 4 : 1;   // batches per attention pass

    // fp32 -> bf16
    cvt_bf16_kernel<<<(M * D / 4 + 255) / 256, 256, 0, stream>>>(x, xb, M * D / 4);
    cvt_bf16_kernel<<<(D * D / 4 + 255) / 256, 256, 0, stream>>>(Wq, Wqb, D * D / 4);
    cvt_bf16_kernel<<<(D * D / 4 + 255) / 256, 256, 0, stream>>>(Wk, Wkb, D * D / 4);
    cvt_bf16_kernel<<<(D * D / 4 + 255) / 256, 256, 0, stream>>>(Wv, Wvb, D * D / 4);
    cvt_bf16_kernel<<<(D * D / 4 + 255) / 256, 256, 0, stream>>>(Wp, Wpb, D * D / 4);

    // q = (x Wq^T + bq) * 1/sqrt(D)   [scale folded into q]
    gemm_nt<1, 1, 0, 0><<<dim3(D / BN, M / BM, 1), 256, 0, stream>>>(
        xb, Wqb, qb, bq, M, D, D, D, D, D, 0, 0, 0, 0.03125f);
    // k = x Wk^T + bk
    gemm_nt<1, 1, 0, 0><<<dim3(D / BN, M / BM, 1), 256, 0, stream>>>(
        xb, Wkb, kb, bk, M, D, D, D, D, D, 0, 0, 0, 1.0f);
    // vT = (x Wv^T + bv)^T  computed directly: vT[d][m] = sum_e Wv[d][e] x[m][e] + bv[d]
    gemm_nt<2, 1, 0, 0><<<dim3(M / BN, D / BM, 1), 256, 0, stream>>>(
        Wvb, xb, vTb, bv, D, M, D, D, D, M, 0, 0, 0, 1.0f);

    for (int b0 = 0; b0 < B; b0 += zb) {
        // scores = q k^T (lower-triangular tiles only)
        gemm_nt<0, 0, 1, 0><<<dim3(S / BN, S / BM, zb), 256, 0, stream>>>(
            qb + (size_t)b0 * S * D, kb + (size_t)b0 * S * D, sc, nullptr,
            S, S, D, D, D, S,
            (long long)S * D, (long long)S * D, (long long)S * S, 1.0f);
        // causal softmax, write P (bf16) in place
        softmax_causal_kernel<<<zb * S, 256, 0, stream>>>(sc, S);
        // attn_out = P v   (A = P bf16 with ld 2S; B = vT rows, K-bounded causally)
        gemm_nt<0, 1, 0, 1><<<dim3(D / BN, S / BM, zb), 256, 0, stream>>>(
            (const u16*)sc, vTb + (size_t)b0 * S, attnb + (size_t)b0 * S * D, nullptr,
            S, D, S, 2 * S, M, D,
            (long long)2 * S * S, (long long)S, (long long)S * D, 1.0f);
    }

    // out = attn_out Wp^T + bp  (fp32 output)
    gemm_nt<1, 0, 0, 0><<<dim3(D / BN, M / BM, 1), 256, 0, stream>>>(
        attnb, Wpb, d_out, bp, M, D, D, D, D, D, 0, 0, 0, 1.0f);
}